// Round 1
// baseline (543.579 us; speedup 1.0000x reference)
//
#include <hip/hip_runtime.h>
#include <hip/hip_bf16.h>

#define NA 8192
#define NB 2048
#define DIM 192
#define NH 4
#define DKH 48
#define TA 16
#define TB 32
#define NTILE 64
#define SCALE 0.14433756729740643f   // 1/sqrt(48)
#define NEGBIG 1e30f

// ---------------- mask dtype detection ----------------
// flag: 0 = int32 {0,1}, 1 = byte (bool8/int8), 2 = float32 {0.0,1.0}
__global__ void maskdetect_kernel(const unsigned int* __restrict__ mw, int* __restrict__ flag) {
  __shared__ int fl;
  if (threadIdx.x == 0) fl = 0;
  __syncthreads();
  for (int i = threadIdx.x; i < 1024; i += 256) {
    unsigned int v = mw[i];
    if (v == 0x3F800000u) atomicMax(&fl, 2);
    else if (v > 1u) atomicMax(&fl, 1);
  }
  __syncthreads();
  if (threadIdx.x == 0) *flag = fl;
}

// ---------------- Q/K/V projections ----------------
// blocks 0..1023: Q (a_z@Wq^T+bq); 1024..1279: K; 1280..1535: V. 8 rows/block.
__global__ __launch_bounds__(192) void proj_kernel(
    const float* __restrict__ a_z, const float* __restrict__ bv_z,
    const float* __restrict__ Wq, const float* __restrict__ Wk, const float* __restrict__ Wv,
    const float* __restrict__ bq, const float* __restrict__ bk, const float* __restrict__ bvb,
    float* __restrict__ Qo, float* __restrict__ Ko, float* __restrict__ Vo)
{
  __shared__ float xs[8][DIM];
  int blk = blockIdx.x;
  const float* src; const float* W; const float* bias; float* dst; int row0;
  if (blk < 1024)      { src = a_z;  W = Wq; bias = bq;  dst = Qo; row0 = blk * 8; }
  else if (blk < 1280) { src = bv_z; W = Wk; bias = bk;  dst = Ko; row0 = (blk - 1024) * 8; }
  else                 { src = bv_z; W = Wv; bias = bvb; dst = Vo; row0 = (blk - 1280) * 8; }
  int t = threadIdx.x;
  for (int i = t; i < 8 * 48; i += 192) {
    int r = i / 48, c = i % 48;
    ((float4*)xs[r])[c] = ((const float4*)(src + (size_t)(row0 + r) * DIM))[c];
  }
  __syncthreads();
  float acc[8];
  float bb = bias[t];
  #pragma unroll
  for (int r = 0; r < 8; ++r) acc[r] = bb;
  const float4* wr = (const float4*)(W + (size_t)t * DIM);
  for (int c = 0; c < 48; ++c) {
    float4 w = wr[c];
    #pragma unroll
    for (int r = 0; r < 8; ++r) {
      float4 x = ((const float4*)xs[r])[c];
      acc[r] += w.x * x.x + w.y * x.y + w.z * x.z + w.w * x.w;
    }
  }
  #pragma unroll
  for (int r = 0; r < 8; ++r) dst[(size_t)(row0 + r) * DIM + t] = acc[r];
}

// ---------------- Wo_eff^T (mean over heads of Wo row-blocks), transposed [192][48] ----------------
__global__ void woe_kernel(const float* __restrict__ Wo, const float* __restrict__ bo,
                           float* __restrict__ WoeT, float* __restrict__ boe)
{
  int i = blockIdx.x * 256 + threadIdx.x;
  if (i < DIM * DKH) {
    int k = i / DKH, d = i % DKH;
    float s = 0.25f * (Wo[(size_t)d * DIM + k] + Wo[(size_t)(d + 48) * DIM + k] +
                       Wo[(size_t)(d + 96) * DIM + k] + Wo[(size_t)(d + 144) * DIM + k]);
    WoeT[k * DKH + d] = s;
  }
  if (i < DKH) boe[i] = 0.25f * (bo[i] + bo[i + 48] + bo[i + 96] + bo[i + 144]);
}

// ---------------- fused attention + influence + topic_align ----------------
__global__ __launch_bounds__(256) void attn_kernel(
    const float* __restrict__ Qg, const float* __restrict__ Kg, const float* __restrict__ Vg,
    const float* __restrict__ weight, const void* __restrict__ maskp,
    const int* __restrict__ maskflag,
    const float* __restrict__ WoeT, const float* __restrict__ boe,
    float* __restrict__ out)
{
  __shared__ float Qs[TA][196];
  __shared__ float Ks[TB][196];
  __shared__ float Vs[TB][196];
  __shared__ float Ss[TA * NH][36];
  __shared__ float Wt[TA][36];
  __shared__ float EWs[TA][36];
  __shared__ float m_s[TA * NH], l_s[TA * NH], A_s[TA * NH];
  __shared__ float Mw_s[TA], Lw_s[TA], aw_s[TA];

  const int t = threadIdx.x;
  const int a0 = blockIdx.x * TA;
  const int pair = t >> 2;   // a*4+h
  const int sub = t & 3;

  float oacc[12];
  #pragma unroll
  for (int i = 0; i < 12; ++i) oacc[i] = 0.f;

  if (t < TA * NH) { m_s[t] = -NEGBIG; l_s[t] = 0.f; A_s[t] = 0.f; }
  if (t < TA) { Mw_s[t] = -NEGBIG; Lw_s[t] = 0.f; }

  for (int i = t; i < TA * 48; i += 256) {
    int r = i / 48, c = i % 48;
    ((float4*)Qs[r])[c] = ((const float4*)(Qg + (size_t)(a0 + r) * DIM))[c];
  }

  const int mmode = *maskflag;
  const unsigned char* m8 = (const unsigned char*)maskp;
  const int* m32 = (const int*)maskp;
  const float* mfp = (const float*)maskp;

  for (int tile = 0; tile < NTILE; ++tile) {
    const int b0 = tile * TB;
    __syncthreads();   // previous tile's PV done; safe to overwrite LDS
    for (int i = t; i < TB * 48; i += 256) {
      int r = i / 48, c = i % 48;
      ((float4*)Ks[r])[c] = ((const float4*)(Kg + (size_t)(b0 + r) * DIM))[c];
      ((float4*)Vs[r])[c] = ((const float4*)(Vg + (size_t)(b0 + r) * DIM))[c];
    }
    for (int i = t; i < TA * TB; i += 256) {
      int a = i >> 5, b = i & 31;
      size_t gi = (size_t)(a0 + a) * NB + (b0 + b);
      bool valid = (mmode == 1) ? (m8[gi] != 0)
                 : (mmode == 2) ? (mfp[gi] != 0.f)
                                : (m32[gi] != 0);
      Wt[a][b] = valid ? weight[gi] : -NEGBIG;
    }
    __syncthreads();

    // ---- QK^T (+w_masked) -> Ss ----
    {
      int a = t >> 4, bs = t & 15;
      const float4* qp = (const float4*)Qs[a];
      const float4* k0 = (const float4*)Ks[bs];
      const float4* k1 = (const float4*)Ks[bs + 16];
      float w0 = Wt[a][bs], w1 = Wt[a][bs + 16];
      #pragma unroll
      for (int h = 0; h < NH; ++h) {
        float s0 = 0.f, s1 = 0.f;
        #pragma unroll
        for (int c = 0; c < 12; ++c) {
          float4 q = qp[h * 12 + c];
          float4 x = k0[h * 12 + c];
          float4 y = k1[h * 12 + c];
          s0 += q.x * x.x + q.y * x.y + q.z * x.z + q.w * x.w;
          s1 += q.x * y.x + q.y * y.y + q.z * y.z + q.w * y.w;
        }
        Ss[a * NH + h][bs]      = s0 * SCALE + w0;   // masked -> exactly -1e30 (f32 absorbs qk)
        Ss[a * NH + h][bs + 16] = s1 * SCALE + w1;
      }
    }
    // ---- weight-softmax running stats (per actor) ----
    {
      int a = t >> 4, j = t & 15;
      float w0 = Wt[a][j], w1 = Wt[a][j + 16];
      float mx = fmaxf(w0, w1);
      #pragma unroll
      for (int o = 1; o < 16; o <<= 1) mx = fmaxf(mx, __shfl_xor(mx, o, 16));
      float Mo = Mw_s[a];
      float Mn = fmaxf(Mo, mx);
      float aw = __expf(Mo - Mn);
      float e0 = (w0 > -1e29f) ? __expf(w0 - Mn) : 0.f;
      float e1 = (w1 > -1e29f) ? __expf(w1 - Mn) : 0.f;
      EWs[a][j] = e0; EWs[a][j + 16] = e1;
      float sm = e0 + e1;
      #pragma unroll
      for (int o = 1; o < 16; o <<= 1) sm += __shfl_xor(sm, o, 16);
      if (j == 0) { Mw_s[a] = Mn; Lw_s[a] = Lw_s[a] * aw + sm; aw_s[a] = aw; }
    }
    __syncthreads();

    // ---- online softmax for this tile (per (a,h) row) ----
    {
      int a = pair >> 2;
      float sv[8];
      float mx = -NEGBIG;
      #pragma unroll
      for (int i = 0; i < 8; ++i) {
        sv[i] = Ss[pair][sub + 4 * i];
        mx = fmaxf(mx, sv[i]);
      }
      mx = fmaxf(mx, __shfl_xor(mx, 1, 4));
      mx = fmaxf(mx, __shfl_xor(mx, 2, 4));
      float mo = m_s[pair];
      float mn = fmaxf(mo, mx);
      float alpha = __expf(mo - mn);
      float ls = 0.f, as = 0.f;
      #pragma unroll
      for (int i = 0; i < 8; ++i) {
        int b = sub + 4 * i;
        float p = (sv[i] > -1e29f) ? __expf(sv[i] - mn) : 0.f;
        Ss[pair][b] = p;      // unnormalized prob for PV
        ls += p;
        as += p * EWs[a][b];  // joint accumulator for influence
      }
      ls += __shfl_xor(ls, 1, 4); ls += __shfl_xor(ls, 2, 4);
      as += __shfl_xor(as, 1, 4); as += __shfl_xor(as, 2, 4);
      #pragma unroll
      for (int i = 0; i < 12; ++i) oacc[i] *= alpha;
      if (sub == 0) {
        m_s[pair] = mn;
        l_s[pair] = l_s[pair] * alpha + ls;
        A_s[pair] = A_s[pair] * alpha * aw_s[a] + as;
      }
    }
    __syncthreads();

    // ---- PV accumulate ----
    {
      int h = pair & 3;
      const int dbase = h * DKH + sub * 12;
      for (int b = 0; b < TB; ++b) {
        float p = Ss[pair][b];
        const float4* vp = (const float4*)(Vs[b] + dbase);
        float4 v0 = vp[0], v1 = vp[1], v2 = vp[2];
        oacc[0] += p * v0.x; oacc[1] += p * v0.y; oacc[2]  += p * v0.z; oacc[3]  += p * v0.w;
        oacc[4] += p * v1.x; oacc[5] += p * v1.y; oacc[6]  += p * v1.z; oacc[7]  += p * v1.w;
        oacc[8] += p * v2.x; oacc[9] += p * v2.y; oacc[10] += p * v2.z; oacc[11] += p * v2.w;
      }
    }
  }

  __syncthreads();
  // normalized attention output rows -> reuse Ks area as Os[TA][196]
  {
    float inv = 1.f / l_s[pair];
    int a = pair >> 2, h = pair & 3;
    float* orow = &Ks[0][0] + a * 196 + h * DKH + sub * 12;
    #pragma unroll
    for (int i = 0; i < 12; ++i) orow[i] = oacc[i] * inv;
  }
  // influence (reads only A_s/l_s/Lw_s, all final)
  if (t < TA) {
    float s = 0.f;
    #pragma unroll
    for (int h = 0; h < NH; ++h) s += A_s[t * NH + h] / l_s[t * NH + h];
    out[(size_t)(a0 + t) * 49 + 48] = s / (4.f * Lw_s[t]);
  }
  __syncthreads();
  // topic_align = Os @ WoeT + boe
  const float* Os = &Ks[0][0];
  for (int i = t; i < TA * DKH; i += 256) {
    int a = i / DKH, dd = i % DKH;
    const float* orow = Os + a * 196;
    float acc = boe[dd];
    for (int k = 0; k < DIM; ++k) acc += orow[k] * WoeT[k * DKH + dd];
    out[(size_t)(a0 + a) * 49 + dd] = acc;
  }
}

extern "C" void kernel_launch(void* const* d_in, const int* in_sizes, int n_in,
                              void* d_out, int out_size, void* d_ws, size_t ws_size,
                              hipStream_t stream) {
  const float* a_z    = (const float*)d_in[0];
  const float* bv_z   = (const float*)d_in[1];
  const float* weight = (const float*)d_in[2];
  const void*  maskp  = d_in[3];
  const float* Wq = (const float*)d_in[4];
  const float* Wk = (const float*)d_in[5];
  const float* Wv = (const float*)d_in[6];
  const float* Wo = (const float*)d_in[7];
  const float* bq = (const float*)d_in[8];
  const float* bk = (const float*)d_in[9];
  const float* bvb = (const float*)d_in[10];
  const float* bo = (const float*)d_in[11];

  float* ws = (float*)d_ws;
  float* Q    = ws;                          // 8192*192
  float* K    = Q + (size_t)NA * DIM;        // 2048*192
  float* V    = K + (size_t)NB * DIM;        // 2048*192
  float* WoeT = V + (size_t)NB * DIM;        // 192*48
  float* boe  = WoeT + DIM * DKH;            // 48
  int*  mflag = (int*)(boe + 64);

  maskdetect_kernel<<<1, 256, 0, stream>>>((const unsigned int*)maskp, mflag);
  proj_kernel<<<1536, 192, 0, stream>>>(a_z, bv_z, Wq, Wk, Wv, bq, bk, bvb, Q, K, V);
  woe_kernel<<<36, 256, 0, stream>>>(Wo, bo, WoeT, boe);
  attn_kernel<<<512, 256, 0, stream>>>(Q, K, V, weight, maskp, mflag, WoeT, boe, (float*)d_out);
}

// Round 2
// 351.202 us; speedup vs baseline: 1.5478x; 1.5478x over previous
//
#include <hip/hip_runtime.h>
#include <hip/hip_bf16.h>

#define NA 8192
#define NB 2048
#define DIM 192
#define NH 4
#define DKH 48
#define TA 32
#define TB 32
#define NTILE 64
#define SCALE 0.14433756729740643f     // 1/sqrt(48)
#define INVSCALE 6.928203230275509f    // sqrt(48)
#define NEGBIG 1e30f

typedef __bf16 bf16x8 __attribute__((ext_vector_type(8)));
typedef float f32x4 __attribute__((ext_vector_type(4)));

#define MFMA16(a, b, c) __builtin_amdgcn_mfma_f32_16x16x32_bf16(a, b, c, 0, 0, 0)

__device__ __forceinline__ float rmax16(float v) {
  v = fmaxf(v, __shfl_xor(v, 1, 16));
  v = fmaxf(v, __shfl_xor(v, 2, 16));
  v = fmaxf(v, __shfl_xor(v, 4, 16));
  v = fmaxf(v, __shfl_xor(v, 8, 16));
  return v;
}
__device__ __forceinline__ float rsum16(float v) {
  v += __shfl_xor(v, 1, 16);
  v += __shfl_xor(v, 2, 16);
  v += __shfl_xor(v, 4, 16);
  v += __shfl_xor(v, 8, 16);
  return v;
}

// ---------------- mask dtype detection ----------------
// flag: 0 = int32 {0,1}, 1 = byte (bool8/int8), 2 = float32 {0.0,1.0}
__global__ void maskdetect_kernel(const unsigned int* __restrict__ mw, int* __restrict__ flag) {
  __shared__ int fl;
  if (threadIdx.x == 0) fl = 0;
  __syncthreads();
  for (int i = threadIdx.x; i < 1024; i += 256) {
    unsigned int v = mw[i];
    if (v == 0x3F800000u) atomicMax(&fl, 2);
    else if (v > 1u) atomicMax(&fl, 1);
  }
  __syncthreads();
  if (threadIdx.x == 0) *flag = fl;
}

// ---------------- Q/K/V projections -> bf16, MFMA-friendly layouts ----------------
// Q: [NA][4][64] bf16 (per-head K padded 48->64 with zeros)
// K: [4][NB][64] bf16 (head-major, padded)
// V: transposed [192][NB] bf16
__global__ __launch_bounds__(192) void proj_kernel(
    const float* __restrict__ a_z, const float* __restrict__ bv_z,
    const float* __restrict__ Wq, const float* __restrict__ Wk, const float* __restrict__ Wv,
    const float* __restrict__ bq, const float* __restrict__ bk, const float* __restrict__ bvb,
    __bf16* __restrict__ Qo, __bf16* __restrict__ Ko, __bf16* __restrict__ Vo)
{
  __shared__ float xs[8][DIM];
  int blk = blockIdx.x;
  const float* src; const float* W; const float* bias; int row0; int which;
  if (blk < 1024)      { src = a_z;  W = Wq; bias = bq;  row0 = blk * 8;          which = 0; }
  else if (blk < 1280) { src = bv_z; W = Wk; bias = bk;  row0 = (blk - 1024) * 8; which = 1; }
  else                 { src = bv_z; W = Wv; bias = bvb; row0 = (blk - 1280) * 8; which = 2; }
  int t = threadIdx.x;
  for (int i = t; i < 8 * 48; i += 192) {
    int r = i / 48, c = i % 48;
    ((float4*)xs[r])[c] = ((const float4*)(src + (size_t)(row0 + r) * DIM))[c];
  }
  __syncthreads();
  float acc[8];
  float bb = bias[t];
  #pragma unroll
  for (int r = 0; r < 8; ++r) acc[r] = bb;
  const float4* wr = (const float4*)(W + (size_t)t * DIM);
  for (int c = 0; c < 48; ++c) {
    float4 w = wr[c];
    #pragma unroll
    for (int r = 0; r < 8; ++r) {
      float4 x = ((const float4*)xs[r])[c];
      acc[r] += w.x * x.x + w.y * x.y + w.z * x.z + w.w * x.w;
    }
  }
  int h = t / 48, dd = t % 48;
  if (which == 0) {
    #pragma unroll
    for (int r = 0; r < 8; ++r)
      Qo[((size_t)(row0 + r) * 4 + h) * 64 + dd] = (__bf16)acc[r];
    for (int i = t; i < 512; i += 192) {   // zero the K-pad [48,64)
      int r = i >> 6, hh = (i >> 4) & 3, kk = i & 15;
      Qo[((size_t)(row0 + r) * 4 + hh) * 64 + 48 + kk] = (__bf16)0.f;
    }
  } else if (which == 1) {
    #pragma unroll
    for (int r = 0; r < 8; ++r)
      Ko[((size_t)h * NB + row0 + r) * 64 + dd] = (__bf16)acc[r];
    for (int i = t; i < 512; i += 192) {
      int r = i >> 6, hh = (i >> 4) & 3, kk = i & 15;
      Ko[((size_t)hh * NB + row0 + r) * 64 + 48 + kk] = (__bf16)0.f;
    }
  } else {
    bf16x8 pk;
    #pragma unroll
    for (int r = 0; r < 8; ++r) pk[r] = (__bf16)acc[r];
    *(bf16x8*)(Vo + (size_t)t * NB + row0) = pk;   // transposed, 16B packed store
  }
}

// ---------------- Wo_eff^T ----------------
__global__ void woe_kernel(const float* __restrict__ Wo, const float* __restrict__ bo,
                           float* __restrict__ WoeT, float* __restrict__ boe)
{
  int i = blockIdx.x * 256 + threadIdx.x;
  if (i < DIM * DKH) {
    int k = i / DKH, d = i % DKH;
    float s = 0.25f * (Wo[(size_t)d * DIM + k] + Wo[(size_t)(d + 48) * DIM + k] +
                       Wo[(size_t)(d + 96) * DIM + k] + Wo[(size_t)(d + 144) * DIM + k]);
    WoeT[k * DKH + d] = s;
  }
  if (i < DKH) boe[i] = 0.25f * (bo[i] + bo[i + 48] + bo[i + 96] + bo[i + 144]);
}

// ---------------- fused MFMA attention + influence + topic_align ----------------
// 256 blocks x 512 threads. Block: 32 actors. Wave wid: h = wid&3, u = wid>>2
// (actor half). Per wave: 16 a-rows x 32 b-cols per tile via 16x16x32 MFMA.
__global__ __launch_bounds__(512, 2) void attn_kernel(
    const __bf16* __restrict__ Qb, const __bf16* __restrict__ Kb, const __bf16* __restrict__ Vtg,
    const float* __restrict__ weight, const void* __restrict__ maskp,
    const int* __restrict__ maskflag,
    const float* __restrict__ WoeT, const float* __restrict__ boe,
    float* __restrict__ out)
{
  // Ks [4][32][72] bf16 (18432 B) + Vt [192][40] bf16 (15360 B) = 33792 B,
  // reused as Os [32][200] f32 (25600 B) in the epilogue.
  __shared__ __align__(16) char smraw[33792];
  __shared__ __bf16 Ss[8][16][40];          // per-wave P staging (C->A layout)
  __shared__ float AfinS[NH][TA], LfinS[NH][TA], LwS[TA];

  __bf16* KsP = (__bf16*)smraw;             // [4][32][72]
  __bf16* VtP = (__bf16*)(smraw + 18432);   // [192][40]

  const int t = threadIdx.x;
  const int lane = t & 63;
  const int wid = t >> 6;
  const int h = wid & 3;
  const int u = wid >> 2;
  const int c = lane & 15;
  const int g = lane >> 4;
  const int g8 = g * 8;
  const int a0 = blockIdx.x * TA;

  const int mmode = *maskflag;

  // Q A-fragments (row = lane&15, k contiguous), hoisted for all 64 tiles
  const __bf16* qp = Qb + ((size_t)(a0 + u * 16 + c) * 4 + h) * 64 + g8;
  const bf16x8 qf0 = *(const bf16x8*)qp;
  const bf16x8 qf1 = *(const bf16x8*)(qp + 32);

  // running stats, rows g*4+j (C-fragment row layout), replicated over c
  float m[4], l[4], A[4], Mw[4], Lw[4];
  #pragma unroll
  for (int j = 0; j < 4; ++j) { m[j] = -NEGBIG; l[j] = 0.f; A[j] = 0.f; Mw[j] = -NEGBIG; Lw[j] = 0.f; }
  f32x4 o0 = {0.f, 0.f, 0.f, 0.f}, o1 = {0.f, 0.f, 0.f, 0.f}, o2 = {0.f, 0.f, 0.f, 0.f};

  const int awbase = a0 + u * 16 + g * 4;

  for (int tile = 0; tile < NTILE; ++tile) {
    const int b0 = tile * TB;
    __syncthreads();   // previous tile fully consumed
    // ---- stage K tile: [4][32][64] -> Ks[4][32][72] ----
    for (int i = t; i < 1024; i += 512) {
      int hh = i >> 8, bb = (i >> 3) & 31, kc = i & 7;
      *(bf16x8*)(KsP + ((hh * 32 + bb) * 72) + kc * 8) =
          *(const bf16x8*)(Kb + ((size_t)hh * NB + b0 + bb) * 64 + kc * 8);
    }
    // ---- stage V^T tile: Vtg[192][b0..b0+32) -> Vt[192][40] ----
    for (int i = t; i < 768; i += 512) {
      int d = i >> 2, bc = i & 3;
      *(bf16x8*)(VtP + d * 40 + bc * 8) =
          *(const bf16x8*)(Vtg + (size_t)d * NB + b0 + bc * 8);
    }
    // ---- masked weight -> registers (C-fragment layout) ----
    float wv0[4], wv1[4];
    #pragma unroll
    for (int j = 0; j < 4; ++j) {
      size_t gi = (size_t)(awbase + j) * NB + b0 + c;
      bool ok0, ok1;
      if (mmode == 1)      { ok0 = ((const unsigned char*)maskp)[gi] != 0;  ok1 = ((const unsigned char*)maskp)[gi + 16] != 0; }
      else if (mmode == 2) { ok0 = ((const float*)maskp)[gi] != 0.f;        ok1 = ((const float*)maskp)[gi + 16] != 0.f; }
      else                 { ok0 = ((const int*)maskp)[gi] != 0;            ok1 = ((const int*)maskp)[gi + 16] != 0; }
      float w0 = weight[gi], w1 = weight[gi + 16];
      wv0[j] = ok0 ? w0 : -NEGBIG;
      wv1[j] = ok1 ? w1 : -NEGBIG;
    }
    __syncthreads();

    // ---- QK^T via MFMA, accumulator seeded with w/scale ----
    const __bf16* krow = KsP + (h * 32 + c) * 72;
    bf16x8 kA0 = *(const bf16x8*)(krow + g8);
    bf16x8 kA1 = *(const bf16x8*)(krow + 32 + g8);
    bf16x8 kB0 = *(const bf16x8*)(krow + 16 * 72 + g8);
    bf16x8 kB1 = *(const bf16x8*)(krow + 16 * 72 + 32 + g8);
    f32x4 acc0, acc1;
    #pragma unroll
    for (int j = 0; j < 4; ++j) { acc0[j] = wv0[j] * INVSCALE; acc1[j] = wv1[j] * INVSCALE; }
    acc0 = MFMA16(qf0, kA0, acc0);
    acc0 = MFMA16(qf1, kA1, acc0);
    acc1 = MFMA16(qf0, kB0, acc1);
    acc1 = MFMA16(qf1, kB1, acc1);

    // ---- weight-softmax running stats (per actor row, in-register) ----
    float ew0[4], ew1[4], awk[4];
    #pragma unroll
    for (int j = 0; j < 4; ++j) {
      float wm = rmax16(fmaxf(wv0[j], wv1[j]));
      float Mwn = fmaxf(Mw[j], wm);
      awk[j] = __expf(Mw[j] - Mwn);
      ew0[j] = __expf(wv0[j] - Mwn);
      ew1[j] = __expf(wv1[j] - Mwn);
      Lw[j] = Lw[j] * awk[j] + rsum16(ew0[j] + ew1[j]);
      Mw[j] = Mwn;
    }
    // ---- online softmax + joint influence accumulator + P write ----
    #pragma unroll
    for (int j = 0; j < 4; ++j) {
      float s0 = acc0[j] * SCALE, s1 = acc1[j] * SCALE;
      float mn = fmaxf(m[j], rmax16(fmaxf(s0, s1)));
      float al = __expf(m[j] - mn);
      float p0 = __expf(s0 - mn), p1 = __expf(s1 - mn);
      l[j] = l[j] * al + rsum16(p0 + p1);
      A[j] = A[j] * al * awk[j] + rsum16(p0 * ew0[j] + p1 * ew1[j]);
      m[j] = mn;
      o0[j] *= al; o1[j] *= al; o2[j] *= al;
      Ss[wid][g * 4 + j][c]      = (__bf16)p0;
      Ss[wid][g * 4 + j][c + 16] = (__bf16)p1;
    }
    __builtin_amdgcn_sched_barrier(0);   // fence cross-lane LDS reuse (wave-private)

    // ---- PV via MFMA: A = P (a x b), B = V (b x d) from Vt ----
    bf16x8 pa = *(const bf16x8*)&Ss[wid][c][g8];
    const __bf16* vrow = VtP + (h * 48 + c) * 40 + g8;
    bf16x8 vf0 = *(const bf16x8*)vrow;
    bf16x8 vf1 = *(const bf16x8*)(vrow + 16 * 40);
    bf16x8 vf2 = *(const bf16x8*)(vrow + 32 * 40);
    o0 = MFMA16(pa, vf0, o0);
    o1 = MFMA16(pa, vf1, o1);
    o2 = MFMA16(pa, vf2, o2);
  }

  __syncthreads();   // everyone done with Ks/Vt; safe to overwrite with Os
  float* Os = (float*)smraw;   // [32][200]
  #pragma unroll
  for (int j = 0; j < 4; ++j) {
    float inv = 1.f / l[j];
    int row = u * 16 + g * 4 + j;
    Os[row * 200 + h * 48 + c]      = o0[j] * inv;
    Os[row * 200 + h * 48 + 16 + c] = o1[j] * inv;
    Os[row * 200 + h * 48 + 32 + c] = o2[j] * inv;
  }
  if (c == 0) {
    #pragma unroll
    for (int j = 0; j < 4; ++j) {
      int row = u * 16 + g * 4 + j;
      AfinS[h][row] = A[j];
      LfinS[h][row] = l[j];
      if (h == 0) LwS[row] = Lw[j];
    }
  }
  __syncthreads();
  if (t < TA) {
    float s = 0.f;
    #pragma unroll
    for (int hh = 0; hh < NH; ++hh) s += AfinS[hh][t] / LfinS[hh][t];
    out[(size_t)(a0 + t) * 49 + 48] = s / (4.f * LwS[t]);
  }
  for (int i = t; i < TA * DKH; i += 512) {
    int a = i / DKH, dd = i % DKH;
    float acc = boe[dd];
    const float* orow = Os + a * 200;
    for (int k = 0; k < DIM; ++k) acc += orow[k] * WoeT[k * DKH + dd];
    out[(size_t)(a0 + a) * 49 + dd] = acc;
  }
}

extern "C" void kernel_launch(void* const* d_in, const int* in_sizes, int n_in,
                              void* d_out, int out_size, void* d_ws, size_t ws_size,
                              hipStream_t stream) {
  const float* a_z    = (const float*)d_in[0];
  const float* bv_z   = (const float*)d_in[1];
  const float* weight = (const float*)d_in[2];
  const void*  maskp  = d_in[3];
  const float* Wq = (const float*)d_in[4];
  const float* Wk = (const float*)d_in[5];
  const float* Wv = (const float*)d_in[6];
  const float* Wo = (const float*)d_in[7];
  const float* bq = (const float*)d_in[8];
  const float* bk = (const float*)d_in[9];
  const float* bvb = (const float*)d_in[10];
  const float* bo = (const float*)d_in[11];

  __bf16* Qb  = (__bf16*)d_ws;                      // [NA][4][64]
  __bf16* Kb  = Qb + (size_t)NA * 256;              // [4][NB][64]
  __bf16* Vtg = Kb + (size_t)4 * NB * 64;           // [192][NB]
  float* WoeT = (float*)(Vtg + (size_t)DIM * NB);   // [192][48]
  float* boe  = WoeT + DIM * DKH;
  int*  mflag = (int*)(boe + 64);

  maskdetect_kernel<<<1, 256, 0, stream>>>((const unsigned int*)maskp, mflag);
  proj_kernel<<<1536, 192, 0, stream>>>(a_z, bv_z, Wq, Wk, Wv, bq, bk, bvb, Qb, Kb, Vtg);
  woe_kernel<<<36, 256, 0, stream>>>(Wo, bo, WoeT, boe);
  attn_kernel<<<NA / TA, 512, 0, stream>>>(Qb, Kb, Vtg, weight, maskp, mflag, WoeT, boe, (float*)d_out);
}

// Round 3
// 345.977 us; speedup vs baseline: 1.5711x; 1.0151x over previous
//
#include <hip/hip_runtime.h>
#include <hip/hip_bf16.h>

#define NA 8192
#define NB 2048
#define DIM 192
#define NH 4
#define DKH 48
#define TA 16
#define TB 32
#define NSPLIT 2
#define TPS 32                         // tiles per split = NB/TB/NSPLIT
#define PREC 208                       // floats per partial record
#define SCALE 0.14433756729740643f     // 1/sqrt(48)
#define INVSCALE 6.928203230275509f    // sqrt(48)
#define NEGBIG 1e30f

typedef __bf16 bf16x8 __attribute__((ext_vector_type(8)));
typedef float f32x4 __attribute__((ext_vector_type(4)));

#define MFMA16(a, b, c) __builtin_amdgcn_mfma_f32_16x16x32_bf16(a, b, c, 0, 0, 0)

// reduce over the g-dimension (lanes differing in bits 4,5); values replicated after
__device__ __forceinline__ float rmaxg(float v) {
  v = fmaxf(v, __shfl_xor(v, 16, 64));
  v = fmaxf(v, __shfl_xor(v, 32, 64));
  return v;
}
__device__ __forceinline__ float rsumg(float v) {
  v += __shfl_xor(v, 16, 64);
  v += __shfl_xor(v, 32, 64);
  return v;
}

// ---------------- mask dtype detection ----------------
// flag: 0 = int32 {0,1}, 1 = byte (bool8/int8), 2 = float32 {0.0,1.0}
__global__ void maskdetect_kernel(const unsigned int* __restrict__ mw, int* __restrict__ flag) {
  __shared__ int fl;
  if (threadIdx.x == 0) fl = 0;
  __syncthreads();
  for (int i = threadIdx.x; i < 1024; i += 256) {
    unsigned int v = mw[i];
    if (v == 0x3F800000u) atomicMax(&fl, 2);
    else if (v > 1u) atomicMax(&fl, 1);
  }
  __syncthreads();
  if (threadIdx.x == 0) *flag = fl;
}

// ---------------- Q/K/V projections -> bf16, MFMA-friendly layouts ----------------
// Q: [NA][4][64] bf16 (per-head K padded 48->64 with zeros)
// K: [4][NB][64] bf16 (head-major, padded)
// V: transposed [192][NB] bf16
__global__ __launch_bounds__(192) void proj_kernel(
    const float* __restrict__ a_z, const float* __restrict__ bv_z,
    const float* __restrict__ Wq, const float* __restrict__ Wk, const float* __restrict__ Wv,
    const float* __restrict__ bq, const float* __restrict__ bk, const float* __restrict__ bvb,
    __bf16* __restrict__ Qo, __bf16* __restrict__ Ko, __bf16* __restrict__ Vo)
{
  __shared__ float xs[8][DIM];
  int blk = blockIdx.x;
  const float* src; const float* W; const float* bias; int row0; int which;
  if (blk < 1024)      { src = a_z;  W = Wq; bias = bq;  row0 = blk * 8;          which = 0; }
  else if (blk < 1280) { src = bv_z; W = Wk; bias = bk;  row0 = (blk - 1024) * 8; which = 1; }
  else                 { src = bv_z; W = Wv; bias = bvb; row0 = (blk - 1280) * 8; which = 2; }
  int t = threadIdx.x;
  for (int i = t; i < 8 * 48; i += 192) {
    int r = i / 48, c = i % 48;
    ((float4*)xs[r])[c] = ((const float4*)(src + (size_t)(row0 + r) * DIM))[c];
  }
  __syncthreads();
  float acc[8];
  float bb = bias[t];
  #pragma unroll
  for (int r = 0; r < 8; ++r) acc[r] = bb;
  const float4* wr = (const float4*)(W + (size_t)t * DIM);
  for (int c = 0; c < 48; ++c) {
    float4 w = wr[c];
    #pragma unroll
    for (int r = 0; r < 8; ++r) {
      float4 x = ((const float4*)xs[r])[c];
      acc[r] += w.x * x.x + w.y * x.y + w.z * x.z + w.w * x.w;
    }
  }
  int h = t / 48, dd = t % 48;
  if (which == 0) {
    #pragma unroll
    for (int r = 0; r < 8; ++r)
      Qo[((size_t)(row0 + r) * 4 + h) * 64 + dd] = (__bf16)acc[r];
    for (int i = t; i < 512; i += 192) {   // zero the K-pad [48,64)
      int r = i >> 6, hh = (i >> 4) & 3, kk = i & 15;
      Qo[((size_t)(row0 + r) * 4 + hh) * 64 + 48 + kk] = (__bf16)0.f;
    }
  } else if (which == 1) {
    #pragma unroll
    for (int r = 0; r < 8; ++r)
      Ko[((size_t)h * NB + row0 + r) * 64 + dd] = (__bf16)acc[r];
    for (int i = t; i < 512; i += 192) {
      int r = i >> 6, hh = (i >> 4) & 3, kk = i & 15;
      Ko[((size_t)hh * NB + row0 + r) * 64 + 48 + kk] = (__bf16)0.f;
    }
  } else {
    bf16x8 pk;
    #pragma unroll
    for (int r = 0; r < 8; ++r) pk[r] = (__bf16)acc[r];
    *(bf16x8*)(Vo + (size_t)t * NB + row0) = pk;   // transposed, 16B packed store
  }
}

// ---------------- Wo_eff^T ----------------
__global__ void woe_kernel(const float* __restrict__ Wo, const float* __restrict__ bo,
                           float* __restrict__ WoeT, float* __restrict__ boe)
{
  int i = blockIdx.x * 256 + threadIdx.x;
  if (i < DIM * DKH) {
    int k = i / DKH, d = i % DKH;
    float s = 0.25f * (Wo[(size_t)d * DIM + k] + Wo[(size_t)(d + 48) * DIM + k] +
                       Wo[(size_t)(d + 96) * DIM + k] + Wo[(size_t)(d + 144) * DIM + k]);
    WoeT[k * DKH + d] = s;
  }
  if (i < DKH) boe[i] = 0.25f * (bo[i] + bo[i + 48] + bo[i + 96] + bo[i + 144]);
}

// ---------------- fused MFMA attention (split-K partials) ----------------
// grid = NSPLIT * (NA/TA) blocks x 256 threads. Wave wid = head h.
// Swapped MFMA: S^T = K*Q^T  (C col = actor = lane&15), O^T = V^T * P^T.
// No __syncthreads in the whole kernel; P round-trip LDS is wave-private.
__global__ __launch_bounds__(256, 4) void attn_kernel(
    const __bf16* __restrict__ Qb, const __bf16* __restrict__ Kb, const __bf16* __restrict__ Vtg,
    const float* __restrict__ weight, const void* __restrict__ maskp,
    const int* __restrict__ maskflag,
    float* __restrict__ part)
{
  __shared__ __bf16 Ss[4][16][40];   // per-wave P staging [a][b]

  const int t = threadIdx.x;
  const int lane = t & 63;
  const int h = t >> 6;
  const int c = lane & 15;          // actor col (and V/K fragment row)
  const int g = lane >> 4;
  const int g8 = g * 8;
  const int nab = NA / TA;          // 512
  const int s = blockIdx.x >> 9;    // split
  const int a0 = (blockIdx.x & (nab - 1)) * TA;
  const int tile0 = s * TPS;

  const int mmode = *maskflag;
  const unsigned char* m8 = (const unsigned char*)maskp;
  const int* m32 = (const int*)maskp;
  const float* mfp = (const float*)maskp;

  // Q fragment (B-operand): col a = c, k contiguous
  const __bf16* qp = Qb + ((size_t)(a0 + c) * NH + h) * 64 + g8;
  const bf16x8 qf0 = *(const bf16x8*)qp;
  const bf16x8 qf1 = *(const bf16x8*)(qp + 32);

  float m = -NEGBIG, l = 0.f, A = 0.f, Mw = -NEGBIG, Lw = 0.f;
  f32x4 o0 = {0.f,0.f,0.f,0.f}, o1 = {0.f,0.f,0.f,0.f}, o2 = {0.f,0.f,0.f,0.f};

  for (int tile = tile0; tile < tile0 + TPS; ++tile) {
    const int b0 = tile * TB;
    // ---- masked weight: lane holds b = b0 + g*4 + j (+16), a = a0 + c ----
    float wv[8];
    {
      size_t gi = (size_t)(a0 + c) * NB + b0 + g * 4;
      #pragma unroll
      for (int j = 0; j < 4; ++j) {
        bool ok0, ok1;
        if (mmode == 1)      { ok0 = m8[gi + j] != 0;       ok1 = m8[gi + 16 + j] != 0; }
        else if (mmode == 2) { ok0 = mfp[gi + j] != 0.f;    ok1 = mfp[gi + 16 + j] != 0.f; }
        else                 { ok0 = m32[gi + j] != 0;      ok1 = m32[gi + 16 + j] != 0; }
        wv[j]     = ok0 ? weight[gi + j]      : -NEGBIG;
        wv[4 + j] = ok1 ? weight[gi + 16 + j] : -NEGBIG;
      }
    }
    // ---- K fragments straight from global (L2-resident) ----
    const __bf16* kp = Kb + ((size_t)h * NB + b0 + c) * 64 + g8;
    bf16x8 kA0 = *(const bf16x8*)kp;
    bf16x8 kA1 = *(const bf16x8*)(kp + 32);
    bf16x8 kB0 = *(const bf16x8*)(kp + 16 * 64);
    bf16x8 kB1 = *(const bf16x8*)(kp + 16 * 64 + 32);

    // ---- S^T via MFMA, accumulator seeded with w/scale ----
    f32x4 acc0, acc1;
    #pragma unroll
    for (int j = 0; j < 4; ++j) { acc0[j] = wv[j] * INVSCALE; acc1[j] = wv[4 + j] * INVSCALE; }
    acc0 = MFMA16(kA0, qf0, acc0);
    acc0 = MFMA16(kA1, qf1, acc0);
    acc1 = MFMA16(kB0, qf0, acc1);
    acc1 = MFMA16(kB1, qf1, acc1);

    // ---- weight-softmax running stats (reduce over 8 local + 2 shuffles) ----
    float wm = fmaxf(fmaxf(fmaxf(wv[0], wv[1]), fmaxf(wv[2], wv[3])),
                     fmaxf(fmaxf(wv[4], wv[5]), fmaxf(wv[6], wv[7])));
    wm = rmaxg(wm);
    float Mwn = fmaxf(Mw, wm);
    float awk = __expf(Mw - Mwn);
    float ew[8];
    #pragma unroll
    for (int i = 0; i < 8; ++i) ew[i] = __expf(wv[i] - Mwn);
    float ews = (ew[0] + ew[1]) + (ew[2] + ew[3]) + (ew[4] + ew[5]) + (ew[6] + ew[7]);
    Lw = Lw * awk + rsumg(ews);
    Mw = Mwn;

    // ---- online softmax + joint influence accumulator ----
    float sv[8];
    #pragma unroll
    for (int j = 0; j < 4; ++j) { sv[j] = acc0[j] * SCALE; sv[4 + j] = acc1[j] * SCALE; }
    float mx = fmaxf(fmaxf(fmaxf(sv[0], sv[1]), fmaxf(sv[2], sv[3])),
                     fmaxf(fmaxf(sv[4], sv[5]), fmaxf(sv[6], sv[7])));
    float mn = fmaxf(m, rmaxg(mx));
    float al = __expf(m - mn);
    float p[8];
    #pragma unroll
    for (int i = 0; i < 8; ++i) p[i] = __expf(sv[i] - mn);
    float ls = (p[0] + p[1]) + (p[2] + p[3]) + (p[4] + p[5]) + (p[6] + p[7]);
    float as = (p[0] * ew[0] + p[1] * ew[1]) + (p[2] * ew[2] + p[3] * ew[3]) +
               (p[4] * ew[4] + p[5] * ew[5]) + (p[6] * ew[6] + p[7] * ew[7]);
    l = l * al + rsumg(ls);
    A = A * al * awk + rsumg(as);
    m = mn;
    #pragma unroll
    for (int j = 0; j < 4; ++j) { o0[j] *= al; o1[j] *= al; o2[j] *= al; }

    // ---- P -> Ss[a][b] (bf16), wave-private ----
    #pragma unroll
    for (int i = 0; i < 4; ++i) {
      Ss[h][c][g * 4 + i]      = (__bf16)p[i];
      Ss[h][c][16 + g * 4 + i] = (__bf16)p[4 + i];
    }
    __builtin_amdgcn_sched_barrier(0);
    bf16x8 pb = *(const bf16x8*)&Ss[h][c][g8];   // B-operand: col a = c, k = b contiguous

    // ---- O^T += V^T * P^T ----
    const __bf16* vp = Vtg + ((size_t)(h * 48 + c)) * NB + b0 + g8;
    bf16x8 vf0 = *(const bf16x8*)vp;
    bf16x8 vf1 = *(const bf16x8*)(vp + 16 * NB);
    bf16x8 vf2 = *(const bf16x8*)(vp + 32 * NB);
    o0 = MFMA16(vf0, pb, o0);
    o1 = MFMA16(vf1, pb, o1);
    o2 = MFMA16(vf2, pb, o2);
  }

  // ---- write unnormalized partial record for (split s, actor a0+c) ----
  float* pr = part + ((size_t)s * NA + a0 + c) * PREC;
  #pragma unroll
  for (int j = 0; j < 4; ++j) {
    pr[h * 48 + g * 4 + j]      = o0[j];
    pr[h * 48 + 16 + g * 4 + j] = o1[j];
    pr[h * 48 + 32 + g * 4 + j] = o2[j];
  }
  if (g == 0) {
    pr[192 + h] = m;
    pr[196 + h] = l;
    pr[200 + h] = A;
    if (h == 0) { pr[204] = Mw; pr[205] = Lw; }
  }
}

// ---------------- merge splits + Woe GEMV + influence ----------------
__global__ __launch_bounds__(256) void merge_kernel(
    const float* __restrict__ part, const float* __restrict__ WoeT,
    const float* __restrict__ boe, float* __restrict__ out)
{
  __shared__ float Os[16][200];
  __shared__ float f0s[16][4], f1s[16][4];
  __shared__ float infl[16][4];
  const int t = threadIdx.x;
  const int a0 = blockIdx.x * 16;
  const float* p0 = part + (size_t)a0 * PREC;
  const float* p1 = part + ((size_t)NA + a0) * PREC;

  if (t < 64) {
    int a = t >> 2, hh = t & 3;
    const float* r0 = p0 + (size_t)a * PREC;
    const float* r1 = p1 + (size_t)a * PREC;
    float m0 = r0[192 + hh], l0 = r0[196 + hh], A0 = r0[200 + hh];
    float m1 = r1[192 + hh], l1 = r1[196 + hh], A1 = r1[200 + hh];
    float ms = fmaxf(m0, m1);
    float f0 = __expf(m0 - ms), f1 = __expf(m1 - ms);
    float lst = l0 * f0 + l1 * f1;
    float Mw0 = r0[204], Lw0 = r0[205];
    float Mw1 = r1[204], Lw1 = r1[205];
    float Mws = fmaxf(Mw0, Mw1);
    float g0 = __expf(Mw0 - Mws), g1 = __expf(Mw1 - Mws);
    float Lws = Lw0 * g0 + Lw1 * g1;
    float As = A0 * f0 * g0 + A1 * f1 * g1;
    float li = 1.f / lst;
    f0s[a][hh] = f0 * li;
    f1s[a][hh] = f1 * li;
    infl[a][hh] = As * li / (4.f * Lws);
  }
  __syncthreads();
  if (t < 16)
    out[(size_t)(a0 + t) * 49 + 48] = infl[t][0] + infl[t][1] + infl[t][2] + infl[t][3];
  for (int i = t; i < 16 * 192; i += 256) {
    int a = i / 192, k = i - a * 192, hh = k / 48;
    Os[a][k] = p0[(size_t)a * PREC + k] * f0s[a][hh] + p1[(size_t)a * PREC + k] * f1s[a][hh];
  }
  __syncthreads();
  for (int i = t; i < 16 * 48; i += 256) {
    int a = i / 48, dd = i - a * 48;
    float acc = boe[dd];
    const float* orow = Os[a];
    for (int k = 0; k < DIM; ++k) acc += orow[k] * WoeT[k * DKH + dd];
    out[(size_t)(a0 + a) * 49 + dd] = acc;
  }
}

extern "C" void kernel_launch(void* const* d_in, const int* in_sizes, int n_in,
                              void* d_out, int out_size, void* d_ws, size_t ws_size,
                              hipStream_t stream) {
  const float* a_z    = (const float*)d_in[0];
  const float* bv_z   = (const float*)d_in[1];
  const float* weight = (const float*)d_in[2];
  const void*  maskp  = d_in[3];
  const float* Wq = (const float*)d_in[4];
  const float* Wk = (const float*)d_in[5];
  const float* Wv = (const float*)d_in[6];
  const float* Wo = (const float*)d_in[7];
  const float* bq = (const float*)d_in[8];
  const float* bk = (const float*)d_in[9];
  const float* bvb = (const float*)d_in[10];
  const float* bo = (const float*)d_in[11];

  __bf16* Qb  = (__bf16*)d_ws;                      // [NA][4][64]
  __bf16* Kb  = Qb + (size_t)NA * 256;              // [4][NB][64]
  __bf16* Vtg = Kb + (size_t)4 * NB * 64;           // [192][NB]
  float* WoeT = (float*)(Vtg + (size_t)DIM * NB);   // [192][48]
  float* boe  = WoeT + DIM * DKH;
  int*  mflag = (int*)(boe + 64);
  float* part = (float*)(mflag + 64);               // [NSPLIT][NA][208]

  maskdetect_kernel<<<1, 256, 0, stream>>>((const unsigned int*)maskp, mflag);
  proj_kernel<<<1536, 192, 0, stream>>>(a_z, bv_z, Wq, Wk, Wv, bq, bk, bvb, Qb, Kb, Vtg);
  woe_kernel<<<36, 256, 0, stream>>>(Wo, bo, WoeT, boe);
  attn_kernel<<<NSPLIT * (NA / TA), 256, 0, stream>>>(Qb, Kb, Vtg, weight, maskp, mflag, part);
  merge_kernel<<<NA / 16, 256, 0, stream>>>(part, WoeT, boe, (float*)d_out);
}